// Round 1
// baseline (5883.982 us; speedup 1.0000x reference)
//
#include <hip/hip_runtime.h>

// ---------------------------------------------------------------------------
// GCN 3-layer forward on MI355X.
// Layout of d_ws (floats):
//   A   [N*128]  h buffer (post-GEMM)
//   B   [N*128]  agg / h buffer (ping-pong)
//   C   [N*16]   layer-3 post-GEMM
//   nrm [E]      per-edge norm = dinv[row]*dinv[col]
//   dinv[N]
//   deg [N] (int)
// Total ~60.3 MB.
// ---------------------------------------------------------------------------

__global__ __launch_bounds__(256) void k_deg_init(int* deg, int n) {
    int i = blockIdx.x * 256 + threadIdx.x;
    if (i < n) deg[i] = 1;               // self-loop
}

__global__ __launch_bounds__(256) void k_deg_count(const int* __restrict__ col, int* deg, int e) {
    int i = blockIdx.x * 256 + threadIdx.x;
    if (i < e) atomicAdd(&deg[col[i]], 1);
}

__global__ __launch_bounds__(256) void k_dinv(const int* __restrict__ deg, float* dinv, int n) {
    int i = blockIdx.x * 256 + threadIdx.x;
    if (i < n) dinv[i] = rsqrtf((float)deg[i]);   // deg >= 1 always
}

__global__ __launch_bounds__(256) void k_norm(const int* __restrict__ row, const int* __restrict__ col,
                                              const float* __restrict__ dinv, float* __restrict__ nrm, int e) {
    int i = blockIdx.x * 256 + threadIdx.x;
    if (i < e) nrm[i] = dinv[row[i]] * dinv[col[i]];
}

__global__ __launch_bounds__(256) void k_zero(float4* p, int n4) {
    int i = blockIdx.x * 256 + threadIdx.x;
    if (i < n4) p[i] = make_float4(0.f, 0.f, 0.f, 0.f);
}

// H[n,128] = X[n,128] @ W[128,128]. W + 32-row X tile staged in LDS.
// 256 threads: thread = (rg 0..7, cg 0..31); computes rows rg*4..+3, cols cg*4..+3.
__global__ __launch_bounds__(256) void k_gemm128(const float* __restrict__ X, const float* __restrict__ W,
                                                 float* __restrict__ H, int n) {
    __shared__ float sW[128 * 128];   // 64 KB
    __shared__ float sX[32 * 128];    // 16 KB
    int tid = threadIdx.x;
    for (int i = tid; i < 4096; i += 256)
        ((float4*)sW)[i] = ((const float4*)W)[i];
    int row0 = blockIdx.x * 32;
    for (int i = tid; i < 1024; i += 256) {
        int gr = row0 + (i >> 5);
        ((float4*)sX)[i] = (gr < n) ? ((const float4*)X)[(size_t)gr * 32 + (i & 31)]
                                    : make_float4(0.f, 0.f, 0.f, 0.f);
    }
    __syncthreads();

    int cg = tid & 31;
    int rg = tid >> 5;
    float acc[4][4];
    #pragma unroll
    for (int i = 0; i < 4; ++i)
        #pragma unroll
        for (int j = 0; j < 4; ++j) acc[i][j] = 0.f;

    #pragma unroll 4
    for (int k = 0; k < 128; ++k) {
        float4 w4 = ((const float4*)sW)[k * 32 + cg];
        #pragma unroll
        for (int i = 0; i < 4; ++i) {
            float xv = sX[(rg * 4 + i) * 128 + k];
            acc[i][0] = fmaf(xv, w4.x, acc[i][0]);
            acc[i][1] = fmaf(xv, w4.y, acc[i][1]);
            acc[i][2] = fmaf(xv, w4.z, acc[i][2]);
            acc[i][3] = fmaf(xv, w4.w, acc[i][3]);
        }
    }
    #pragma unroll
    for (int i = 0; i < 4; ++i) {
        int gr = row0 + rg * 4 + i;
        if (gr < n)
            ((float4*)H)[(size_t)gr * 32 + cg] =
                make_float4(acc[i][0], acc[i][1], acc[i][2], acc[i][3]);
    }
}

// H[n,16] = X[n,128] @ W[128,16]. 16 rows/block; thread = (row 0..15, col 0..15).
__global__ __launch_bounds__(256) void k_gemm16(const float* __restrict__ X, const float* __restrict__ W,
                                                float* __restrict__ H, int n) {
    __shared__ float sX[16 * 132];    // padded stride 132 to dodge bank conflicts
    __shared__ float sW[128 * 16];
    int tid = threadIdx.x;
    for (int i = tid; i < 512; i += 256)
        ((float4*)sW)[i] = ((const float4*)W)[i];
    int row0 = blockIdx.x * 16;
    for (int i = tid; i < 512; i += 256) {
        int r = i >> 5, c = i & 31;
        int gr = row0 + r;
        float4 v = (gr < n) ? ((const float4*)X)[(size_t)gr * 32 + c]
                            : make_float4(0.f, 0.f, 0.f, 0.f);
        *(float4*)&sX[r * 132 + c * 4] = v;   // 132*4=528 bytes/row, 16B-aligned
    }
    __syncthreads();

    int rl = tid >> 4, cj = tid & 15;
    float acc = 0.f;
    #pragma unroll 8
    for (int k = 0; k < 128; ++k)
        acc = fmaf(sX[rl * 132 + k], sW[k * 16 + cj], acc);
    int gr = row0 + rl;
    if (gr < n) H[(size_t)gr * 16 + cj] = acc;
}

// agg[col] += norm * H[row], 128-wide: 32 threads/edge, float4 each.
__global__ __launch_bounds__(256) void k_scatter128(const float* __restrict__ H, const int* __restrict__ row,
                                                    const int* __restrict__ col, const float* __restrict__ nrm,
                                                    float* agg, int e) {
    int t = blockIdx.x * 256 + threadIdx.x;
    int ed = t >> 5;
    if (ed >= e) return;
    int c = t & 31;
    int r  = row[ed];
    int cl = col[ed];
    float w = nrm[ed];
    float4 v = ((const float4*)H)[(size_t)r * 32 + c];
    float* dst = agg + (size_t)cl * 128 + c * 4;
    atomicAdd(dst + 0, v.x * w);
    atomicAdd(dst + 1, v.y * w);
    atomicAdd(dst + 2, v.z * w);
    atomicAdd(dst + 3, v.w * w);
}

// 16-wide variant: 4 threads/edge.
__global__ __launch_bounds__(256) void k_scatter16(const float* __restrict__ H, const int* __restrict__ row,
                                                   const int* __restrict__ col, const float* __restrict__ nrm,
                                                   float* agg, int e) {
    int t = blockIdx.x * 256 + threadIdx.x;
    int ed = t >> 2;
    if (ed >= e) return;
    int c = t & 3;
    int r  = row[ed];
    int cl = col[ed];
    float w = nrm[ed];
    float4 v = ((const float4*)H)[(size_t)r * 4 + c];
    float* dst = agg + (size_t)cl * 16 + c * 4;
    atomicAdd(dst + 0, v.x * w);
    atomicAdd(dst + 1, v.y * w);
    atomicAdd(dst + 2, v.z * w);
    atomicAdd(dst + 3, v.w * w);
}

// out = relu(agg + dinv^2 * h + b)   (self-loop folded in; may run in place)
template <int F>
__global__ __launch_bounds__(256) void k_epi(const float* agg, const float* h,
                                             const float* __restrict__ dinv,
                                             const float* __restrict__ b, float* out, int n) {
    constexpr int F4 = F / 4;
    int t = blockIdx.x * 256 + threadIdx.x;
    int i = t / F4, c = t % F4;
    if (i >= n) return;
    float di = dinv[i];
    float s  = di * di;
    float4 a  = ((const float4*)agg)[t];
    float4 hv = ((const float4*)h)[t];
    float4 bv = ((const float4*)b)[c];
    float4 o;
    o.x = fmaxf(fmaf(s, hv.x, a.x) + bv.x, 0.f);
    o.y = fmaxf(fmaf(s, hv.y, a.y) + bv.y, 0.f);
    o.z = fmaxf(fmaf(s, hv.z, a.z) + bv.z, 0.f);
    o.w = fmaxf(fmaf(s, hv.w, a.w) + bv.w, 0.f);
    ((float4*)out)[t] = o;
}

static inline int cdiv(int a, int b) { return (a + b - 1) / b; }

extern "C" void kernel_launch(void* const* d_in, const int* in_sizes, int n_in,
                              void* d_out, int out_size, void* d_ws, size_t ws_size,
                              hipStream_t stream) {
    const float* x  = (const float*)d_in[0];
    const int*   ei = (const int*)d_in[1];
    const float* W1 = (const float*)d_in[2];
    const float* b1 = (const float*)d_in[3];
    const float* W2 = (const float*)d_in[4];
    const float* b2 = (const float*)d_in[5];
    const float* W3 = (const float*)d_in[6];
    const float* b3 = (const float*)d_in[7];

    const int n = in_sizes[0] / 128;
    const int e = in_sizes[1] / 2;
    const int* row = ei;         // source j
    const int* col = ei + e;     // target i

    float* A    = (float*)d_ws;
    float* B    = A + (size_t)n * 128;
    float* C    = B + (size_t)n * 128;
    float* nrm  = C + (size_t)n * 16;
    float* dinv = nrm + e;
    int*   deg  = (int*)(dinv + n);
    float* out  = (float*)d_out;

    // --- norm precompute ---
    k_deg_init <<<cdiv(n, 256), 256, 0, stream>>>(deg, n);
    k_deg_count<<<cdiv(e, 256), 256, 0, stream>>>(col, deg, e);
    k_dinv     <<<cdiv(n, 256), 256, 0, stream>>>(deg, dinv, n);
    k_norm     <<<cdiv(e, 256), 256, 0, stream>>>(row, col, dinv, nrm, e);

    // --- layer 1: x -> A (gemm), scatter A -> B, epi in-place B ---
    k_gemm128  <<<cdiv(n, 32), 256, 0, stream>>>(x, W1, A, n);
    k_zero     <<<cdiv(n * 32, 256), 256, 0, stream>>>((float4*)B, n * 32);
    k_scatter128<<<cdiv(e * 32, 256), 256, 0, stream>>>(A, row, col, nrm, B, e);
    k_epi<128> <<<cdiv(n * 32, 256), 256, 0, stream>>>(B, A, dinv, b1, B, n);

    // --- layer 2 ---
    k_gemm128  <<<cdiv(n, 32), 256, 0, stream>>>(B, W2, A, n);
    k_zero     <<<cdiv(n * 32, 256), 256, 0, stream>>>((float4*)B, n * 32);
    k_scatter128<<<cdiv(e * 32, 256), 256, 0, stream>>>(A, row, col, nrm, B, e);
    k_epi<128> <<<cdiv(n * 32, 256), 256, 0, stream>>>(B, A, dinv, b2, B, n);

    // --- layer 3: B -> C (gemm 16), scatter C -> out, epi in-place out ---
    k_gemm16   <<<cdiv(n, 16), 256, 0, stream>>>(B, W3, C, n);
    k_zero     <<<cdiv(n * 4, 256), 256, 0, stream>>>((float4*)out, n * 4);
    k_scatter16<<<cdiv(e * 4, 256), 256, 0, stream>>>(C, row, col, nrm, out, e);
    k_epi<16>  <<<cdiv(n * 4, 256), 256, 0, stream>>>(out, C, dinv, b3, out, n);
}

// Round 2
// 517.447 us; speedup vs baseline: 11.3712x; 11.3712x over previous
//
#include <hip/hip_runtime.h>

// ---------------------------------------------------------------------------
// GCN 3-layer forward, gather-based (no float atomics).
// Per call: build CSR by destination (count -> scan -> fill), then per layer:
//   GEMM (dense, LDS-staged)  ->  gather-aggregate fused with self-loop+bias+ReLU.
//
// d_ws layout (4-byte units, csr first for int2 alignment):
//   csr  [2*E]  int2 packed (row, norm-bits)
//   A    [N*128] post-GEMM h
//   B    [N*128] layer output
//   C    [N*16]  layer-3 post-GEMM
//   dinv [N]
//   offs [N+1]  int
//   cnt  [N]    int (reused as fill cursor)
//   bsum [256]  int (scan partials)
// Total ~68 MB.
// ---------------------------------------------------------------------------

static inline int cdiv(int a, int b) { return (a + b - 1) / b; }

__global__ __launch_bounds__(256) void k_zero_int(int* p, int n) {
    int i = blockIdx.x * 256 + threadIdx.x;
    if (i < n) p[i] = 0;
}

__global__ __launch_bounds__(256) void k_count(const int* __restrict__ col, int* cnt, int e) {
    int i = blockIdx.x * 256 + threadIdx.x;
    if (i < e) atomicAdd(&cnt[col[i]], 1);
}

__global__ __launch_bounds__(256) void k_dinv(const int* __restrict__ cnt, float* dinv, int n) {
    int i = blockIdx.x * 256 + threadIdx.x;
    if (i < n) dinv[i] = rsqrtf((float)(cnt[i] + 1));   // +1 self-loop
}

// scan kernel A: per-256-chunk sums (chunks cover [0, n+1) virtual elems, cnt[i>=n]=0)
__global__ __launch_bounds__(256) void k_scanA(const int* __restrict__ cnt, int* bsum, int n) {
    __shared__ int s[256];
    int t = threadIdx.x;
    int i = blockIdx.x * 256 + t;
    s[t] = (i < n) ? cnt[i] : 0;
    __syncthreads();
    for (int off = 128; off > 0; off >>= 1) {
        if (t < off) s[t] += s[t + off];
        __syncthreads();
    }
    if (t == 0) bsum[blockIdx.x] = s[0];
}

// scan kernel B: exclusive scan of block sums (single block, nb <= 256)
__global__ __launch_bounds__(256) void k_scanB(int* bsum, int nb) {
    __shared__ int s[256];
    int t = threadIdx.x;
    int v = (t < nb) ? bsum[t] : 0;
    s[t] = v;
    for (int off = 1; off < 256; off <<= 1) {
        __syncthreads();
        int x = (t >= off) ? s[t - off] : 0;
        __syncthreads();
        s[t] += x;
    }
    __syncthreads();
    if (t < nb) bsum[t] = s[t] - v;   // exclusive
}

// scan kernel C: per-chunk exclusive scan + block offset -> offs (covers i in [0, n])
__global__ __launch_bounds__(256) void k_scanC(const int* __restrict__ cnt, const int* __restrict__ bsum,
                                               int* offs, int n) {
    __shared__ int s[256];
    int t = threadIdx.x;
    int i = blockIdx.x * 256 + t;
    int v = (i < n) ? cnt[i] : 0;
    s[t] = v;
    for (int off = 1; off < 256; off <<= 1) {
        __syncthreads();
        int x = (t >= off) ? s[t - off] : 0;
        __syncthreads();
        s[t] += x;
    }
    __syncthreads();
    if (i <= n) offs[i] = bsum[blockIdx.x] + s[t] - v;
}

__global__ __launch_bounds__(256) void k_fill(const int* __restrict__ row, const int* __restrict__ col,
                                              const float* __restrict__ dinv, const int* __restrict__ offs,
                                              int* cur, int2* __restrict__ csr, int e) {
    int i = blockIdx.x * 256 + threadIdx.x;
    if (i >= e) return;
    int c = col[i], r = row[i];
    float w = dinv[r] * dinv[c];
    int pos = offs[c] + atomicAdd(&cur[c], 1);
    csr[pos] = make_int2(r, __float_as_int(w));
}

// H[n,128] = X[n,128] @ W[128,128]; W + 32-row tile in LDS, 4x4 reg blocking.
__global__ __launch_bounds__(256) void k_gemm128(const float* __restrict__ X, const float* __restrict__ W,
                                                 float* __restrict__ H, int n) {
    __shared__ float sW[128 * 128];
    __shared__ float sX[32 * 128];
    int tid = threadIdx.x;
    for (int i = tid; i < 4096; i += 256)
        ((float4*)sW)[i] = ((const float4*)W)[i];
    int row0 = blockIdx.x * 32;
    for (int i = tid; i < 1024; i += 256) {
        int gr = row0 + (i >> 5);
        ((float4*)sX)[i] = (gr < n) ? ((const float4*)X)[(size_t)gr * 32 + (i & 31)]
                                    : make_float4(0.f, 0.f, 0.f, 0.f);
    }
    __syncthreads();

    int cg = tid & 31, rg = tid >> 5;
    float acc[4][4];
    #pragma unroll
    for (int i = 0; i < 4; ++i)
        #pragma unroll
        for (int j = 0; j < 4; ++j) acc[i][j] = 0.f;

    #pragma unroll 4
    for (int k = 0; k < 128; ++k) {
        float4 w4 = ((const float4*)sW)[k * 32 + cg];
        #pragma unroll
        for (int i = 0; i < 4; ++i) {
            float xv = sX[(rg * 4 + i) * 128 + k];
            acc[i][0] = fmaf(xv, w4.x, acc[i][0]);
            acc[i][1] = fmaf(xv, w4.y, acc[i][1]);
            acc[i][2] = fmaf(xv, w4.z, acc[i][2]);
            acc[i][3] = fmaf(xv, w4.w, acc[i][3]);
        }
    }
    #pragma unroll
    for (int i = 0; i < 4; ++i) {
        int gr = row0 + rg * 4 + i;
        if (gr < n)
            ((float4*)H)[(size_t)gr * 32 + cg] =
                make_float4(acc[i][0], acc[i][1], acc[i][2], acc[i][3]);
    }
}

// H[n,16] = X[n,128] @ W[128,16].
__global__ __launch_bounds__(256) void k_gemm16(const float* __restrict__ X, const float* __restrict__ W,
                                                float* __restrict__ H, int n) {
    __shared__ float sX[16 * 132];
    __shared__ float sW[128 * 16];
    int tid = threadIdx.x;
    for (int i = tid; i < 512; i += 256)
        ((float4*)sW)[i] = ((const float4*)W)[i];
    int row0 = blockIdx.x * 16;
    for (int i = tid; i < 512; i += 256) {
        int r = i >> 5, c = i & 31;
        int gr = row0 + r;
        float4 v = (gr < n) ? ((const float4*)X)[(size_t)gr * 32 + c]
                            : make_float4(0.f, 0.f, 0.f, 0.f);
        *(float4*)&sX[r * 132 + c * 4] = v;
    }
    __syncthreads();

    int rl = tid >> 4, cj = tid & 15;
    float acc = 0.f;
    #pragma unroll 8
    for (int k = 0; k < 128; ++k)
        acc = fmaf(sX[rl * 132 + k], sW[k * 16 + cj], acc);
    int gr = row0 + rl;
    if (gr < n) H[(size_t)gr * 16 + cj] = acc;
}

// Gather-aggregate, F=128: one wave per node, lane owns float2.
// out[i] = relu( sum_edges norm*H[row] + dinv[i]^2*H[i] + b )
__global__ __launch_bounds__(256) void k_agg128(const float* __restrict__ H, const int2* __restrict__ csr,
                                                const int* __restrict__ offs, const float* __restrict__ dinv,
                                                const float* __restrict__ b, float* __restrict__ out, int n) {
    int node = (blockIdx.x * 256 + threadIdx.x) >> 6;   // uniform per wave
    if (node >= n) return;
    int lane = threadIdx.x & 63;
    int ed = offs[node], end = offs[node + 1];
    float2 acc = make_float2(0.f, 0.f);
    // 2x manual unroll for load-latency overlap
    for (; ed + 1 < end; ed += 2) {
        int2 p0 = csr[ed], p1 = csr[ed + 1];
        float2 v0 = ((const float2*)(H + (size_t)p0.x * 128))[lane];
        float2 v1 = ((const float2*)(H + (size_t)p1.x * 128))[lane];
        float w0 = __int_as_float(p0.y), w1 = __int_as_float(p1.y);
        acc.x = fmaf(w0, v0.x, acc.x); acc.y = fmaf(w0, v0.y, acc.y);
        acc.x = fmaf(w1, v1.x, acc.x); acc.y = fmaf(w1, v1.y, acc.y);
    }
    if (ed < end) {
        int2 p0 = csr[ed];
        float2 v0 = ((const float2*)(H + (size_t)p0.x * 128))[lane];
        float w0 = __int_as_float(p0.y);
        acc.x = fmaf(w0, v0.x, acc.x); acc.y = fmaf(w0, v0.y, acc.y);
    }
    float di = dinv[node], sl = di * di;
    float2 hv = ((const float2*)(H + (size_t)node * 128))[lane];
    float2 bv = ((const float2*)b)[lane];
    float2 o;
    o.x = fmaxf(fmaf(sl, hv.x, acc.x) + bv.x, 0.f);
    o.y = fmaxf(fmaf(sl, hv.y, acc.y) + bv.y, 0.f);
    ((float2*)(out + (size_t)node * 128))[lane] = o;
}

// Gather-aggregate, F=16: 4 lanes per node, lane owns float4.
__global__ __launch_bounds__(256) void k_agg16(const float* __restrict__ H, const int2* __restrict__ csr,
                                               const int* __restrict__ offs, const float* __restrict__ dinv,
                                               const float* __restrict__ b, float* __restrict__ out, int n) {
    int t = blockIdx.x * 256 + threadIdx.x;
    int node = t >> 2;
    if (node >= n) return;
    int sub = t & 3;
    int ed = offs[node], end = offs[node + 1];
    float4 acc = make_float4(0.f, 0.f, 0.f, 0.f);
    for (; ed < end; ++ed) {
        int2 p = csr[ed];
        float w = __int_as_float(p.y);
        float4 v = ((const float4*)(H + (size_t)p.x * 16))[sub];
        acc.x = fmaf(w, v.x, acc.x); acc.y = fmaf(w, v.y, acc.y);
        acc.z = fmaf(w, v.z, acc.z); acc.w = fmaf(w, v.w, acc.w);
    }
    float di = dinv[node], sl = di * di;
    float4 hv = ((const float4*)(H + (size_t)node * 16))[sub];
    float4 bv = ((const float4*)b)[sub];
    float4 o;
    o.x = fmaxf(fmaf(sl, hv.x, acc.x) + bv.x, 0.f);
    o.y = fmaxf(fmaf(sl, hv.y, acc.y) + bv.y, 0.f);
    o.z = fmaxf(fmaf(sl, hv.z, acc.z) + bv.z, 0.f);
    o.w = fmaxf(fmaf(sl, hv.w, acc.w) + bv.w, 0.f);
    ((float4*)(out + (size_t)node * 16))[t & 3] = o;
}

extern "C" void kernel_launch(void* const* d_in, const int* in_sizes, int n_in,
                              void* d_out, int out_size, void* d_ws, size_t ws_size,
                              hipStream_t stream) {
    const float* x  = (const float*)d_in[0];
    const int*   ei = (const int*)d_in[1];
    const float* W1 = (const float*)d_in[2];
    const float* b1 = (const float*)d_in[3];
    const float* W2 = (const float*)d_in[4];
    const float* b2 = (const float*)d_in[5];
    const float* W3 = (const float*)d_in[6];
    const float* b3 = (const float*)d_in[7];

    const int n = in_sizes[0] / 128;
    const int e = in_sizes[1] / 2;
    const int* row = ei;       // source j
    const int* col = ei + e;   // target i

    int2*  csr  = (int2*)d_ws;
    float* A    = (float*)(csr + e);
    float* B    = A + (size_t)n * 128;
    float* C    = B + (size_t)n * 128;
    float* dinv = C + (size_t)n * 16;
    int*   offs = (int*)(dinv + n);
    int*   cnt  = offs + (n + 1);
    int*   bsum = cnt + n;
    float* out  = (float*)d_out;

    const int nb = cdiv(n + 1, 256);   // scan chunks covering [0, n]

    // --- CSR build ---
    k_zero_int<<<cdiv(n, 256), 256, 0, stream>>>(cnt, n);
    k_count   <<<cdiv(e, 256), 256, 0, stream>>>(col, cnt, e);
    k_dinv    <<<cdiv(n, 256), 256, 0, stream>>>(cnt, dinv, n);
    k_scanA   <<<nb, 256, 0, stream>>>(cnt, bsum, n);
    k_scanB   <<<1, 256, 0, stream>>>(bsum, nb);
    k_scanC   <<<nb, 256, 0, stream>>>(cnt, bsum, offs, n);
    k_zero_int<<<cdiv(n, 256), 256, 0, stream>>>(cnt, n);   // reuse as cursor
    k_fill    <<<cdiv(e, 256), 256, 0, stream>>>(row, col, dinv, offs, cnt, csr, e);

    // --- layer 1 ---
    k_gemm128<<<cdiv(n, 32), 256, 0, stream>>>(x, W1, A, n);
    k_agg128 <<<cdiv(n * 64, 256), 256, 0, stream>>>(A, csr, offs, dinv, b1, B, n);
    // --- layer 2 ---
    k_gemm128<<<cdiv(n, 32), 256, 0, stream>>>(B, W2, A, n);
    k_agg128 <<<cdiv(n * 64, 256), 256, 0, stream>>>(A, csr, offs, dinv, b2, B, n);
    // --- layer 3 ---
    k_gemm16 <<<cdiv(n, 16), 256, 0, stream>>>(B, W3, C, n);
    k_agg16  <<<cdiv(n * 4, 256), 256, 0, stream>>>(C, csr, offs, dinv, b3, out, n);
}